// Round 26
// baseline (91.476 us; speedup 1.0000x reference)
//
#include <hip/hip_runtime.h>
#include <hip/hip_bf16.h>
#include <math.h>

typedef __attribute__((ext_vector_type(8))) short bf16x8;
typedef __attribute__((ext_vector_type(4))) float f32x4;

#define WSTR 68     // G-buffer row stride in shorts (136B): conflict-free frag reads
#define OSTR 80     // out-stage row stride in floats: 3*80 % 32 == 16 -> 2-way (free)

__device__ __forceinline__ short f2bs(float f) {   // fp32 -> bf16 RNE via hw cvt
    union { __hip_bfloat16 b; short s; } u;
    u.b = __float2bfloat16(f);
    return u.s;
}

// gelu(x) = x*sigmoid(2y), y = 0.7978845608*x*(1+0.044715*x^2)   (tanh-form, hw exp2)
__device__ __forceinline__ float gelu_t(float x) {
    float x2 = x * x;
    float z  = x * fmaf(0.10294324f, x2, 2.3022082f);
    float e  = __builtin_amdgcn_exp2f(z);
    float r  = __builtin_amdgcn_rcpf(1.0f + e);
    return fmaf(x, -r, x);          // x*(1-r)
}

// W1/W2 fragment from swizzled LDS tile: 16B-granular XOR swizzle
#define WFRAG(Ws, row, ks) \
    (*(const bf16x8*)&(Ws)[(row) * 64 + ((((ks)*32) + q*8) ^ (((row) & 7) << 3))])

// Single-dispatch kernel: weights staged from fp32 sources in-block (transposed
// gather, L2/L3-hot), softmax(edge_attn) computed in-kernel. No prep dispatch.
__global__ __launch_bounds__(256, 3)
void edge_mfma21(const float* __restrict__ nodes,
                 const float* __restrict__ W1,     // [128][64] fp32
                 const float* __restrict__ b1,
                 const float* __restrict__ W2,     // [64][64] fp32
                 const float* __restrict__ b2,
                 const float* __restrict__ ea,     // [3][3] fp32
                 float* __restrict__ out)
{
    __shared__ __align__(16) unsigned short Ws1[8192];  // 16 KB swizzled W1cat^T
    __shared__ __align__(16) unsigned short Ws2[4096];  //  8 KB swizzled W2^T
    __shared__ __align__(16) float Un[4 * 12 * OSTR];   // 15.36 KB Gw/Ow union
    // total 39936 B -> 4 blocks/CU (occupancy non-binding per R16/R21)

    const int t = threadIdx.x;
    const int lane = t & 63, wave = t >> 6;
    const int q = lane >> 4, r16 = lane & 15;
    float*          Ow = Un + wave * 12 * OSTR;          // wave-private
    unsigned short* Gw = (unsigned short*)Ow;            // aliased, same bytes

    // ---- stage W1cat^T -> Ws1 (1024 chunks), W2^T -> Ws2 (512 chunks) ----
    // chunk c: col n = c>>3, k-octet k8 = c&7; src = 8 stride-64 fp32 elems.
    #pragma unroll
    for (int i = 0; i < 4; ++i) {
        int c = t + i * 256;
        int n = c >> 3, k8 = c & 7;
        const float* src = (n < 64) ? (W1 + (k8 * 8) * 64 + n)
                                    : (W1 + (64 + k8 * 8) * 64 + (n - 64));
        bf16x8 pk;
        #pragma unroll
        for (int e = 0; e < 8; ++e) pk[e] = f2bs(src[e * 64]);
        *(bf16x8*)&Ws1[((c & ~7) | (k8 ^ (n & 7))) * 8] = pk;
    }
    #pragma unroll
    for (int i = 0; i < 2; ++i) {
        int c = t + i * 256;
        int n = c >> 3, k8 = c & 7;
        const float* src = W2 + (k8 * 8) * 64 + n;
        bf16x8 pk;
        #pragma unroll
        for (int e = 0; e < 8; ++e) pk[e] = f2bs(src[e * 64]);
        *(bf16x8*)&Ws2[((c & ~7) | (k8 ^ (n & 7))) * 8] = pk;
    }

    // padded tile row r16 -> batch-in-group bA, node-row iA (iA==3 is the dummy row)
    const int bA = r16 >> 2;
    const int iA = r16 & 3;
    const int iAr = (iA == 3) ? 0 : iA;

    // ---- softmax(edge_attn) in-kernel, SGPR-pinned (wave-uniform) ----
    float aw[9];
    {
        float e_[9];
        #pragma unroll
        for (int i = 0; i < 9; ++i) e_[i] = ea[i];
        #pragma unroll
        for (int i = 0; i < 3; ++i) {
            float mx = fmaxf(e_[i*3+0], fmaxf(e_[i*3+1], e_[i*3+2]));
            float x0 = __builtin_amdgcn_exp2f((e_[i*3+0] - mx) * 1.44269504f);
            float x1 = __builtin_amdgcn_exp2f((e_[i*3+1] - mx) * 1.44269504f);
            float x2 = __builtin_amdgcn_exp2f((e_[i*3+2] - mx) * 1.44269504f);
            float inv = 1.0f / (x0 + x1 + x2);
            aw[i*3+0] = x0 * inv; aw[i*3+1] = x1 * inv; aw[i*3+2] = x2 * inv;
        }
        #pragma unroll
        for (int i = 0; i < 9; ++i) {
            union { float f; int u; } c; c.f = aw[i];
            c.u = __builtin_amdgcn_readfirstlane(c.u);
            aw[i] = c.f;
        }
    }
    float b1c[4], b2c[4];
    #pragma unroll
    for (int nt = 0; nt < 4; ++nt) { b1c[nt] = b1[nt*16 + r16]; b2c[nt] = b2[nt*16 + r16]; }

    const int batch0 = blockIdx.x * 64 + wave * 16;

    __syncthreads();   // weights staged

    // W2 fragments from LDS (held in regs; LDS re-read if sunk — cheap either way)
    bf16x8 w2f[4][2];
    #pragma unroll
    for (int nt = 0; nt < 4; ++nt) {
        w2f[nt][0] = WFRAG(Ws2, nt*16 + r16, 0);
        w2f[nt][1] = WFRAG(Ws2, nt*16 + r16, 1);
    }

    #pragma unroll
    for (int mt = 0; mt < 4; ++mt) {
        const int bb = batch0 + mt * 4;                   // this iter's 4 batches

        // ---- X -> A-frags straight from global (k = ks*32 + q*8 + e) ----
        const long rowA = ((long)(bb + bA)) * 3 + iAr;
        const f32x4* xp = (const f32x4*)(nodes + rowA * 64 + q * 8);
        f32x4 x0 = xp[0], x1 = xp[1], x2v = xp[8], x3 = xp[9];
        bf16x8 afr0, afr1;
        #pragma unroll
        for (int e = 0; e < 4; ++e) {
            afr0[e]   = f2bs(x0[e]);  afr0[4+e] = f2bs(x1[e]);
            afr1[e]   = f2bs(x2v[e]); afr1[4+e] = f2bs(x3[e]);
        }

        // ---- GEMM1 + lane-local gelu mix; MFMA cluster under setprio(1) ----
        #pragma unroll
        for (int nt = 0; nt < 4; ++nt) {
            __builtin_amdgcn_s_setprio(1);
            f32x4 z = {0.f, 0.f, 0.f, 0.f};
            z = __builtin_amdgcn_mfma_f32_16x16x32_bf16(afr0, WFRAG(Ws1, nt*16 + r16, 0), z, 0, 0, 0);
            z = __builtin_amdgcn_mfma_f32_16x16x32_bf16(afr1, WFRAG(Ws1, nt*16 + r16, 1), z, 0, 0, 0);
            f32x4 y = {0.f, 0.f, 0.f, 0.f};
            y = __builtin_amdgcn_mfma_f32_16x16x32_bf16(afr0, WFRAG(Ws1, 64 + nt*16 + r16, 0), y, 0, 0, 0);
            y = __builtin_amdgcn_mfma_f32_16x16x32_bf16(afr1, WFRAG(Ws1, 64 + nt*16 + r16, 1), y, 0, 0, 0);
            __builtin_amdgcn_s_setprio(0);

            // lane holds batch q: u rows z[0..2], v rows y[0..2], col nt*16+r16
            float u0 = z[0] + b1c[nt], u1 = z[1] + b1c[nt], u2 = z[2] + b1c[nt];
            float gg0 = 0.f, gg1 = 0.f, gg2 = 0.f;
            #pragma unroll
            for (int j = 0; j < 3; ++j) {
                float vj = y[j];
                float gl0 = gelu_t(u0 + vj);
                float gl1 = gelu_t(u1 + vj);
                float gl2 = gelu_t(u2 + vj);
                gg0 = fmaf(aw[0*3+j], gl0, gg0);
                gg1 = fmaf(aw[1*3+j], gl1, gg1);
                gg2 = fmaf(aw[2*3+j], gl2, gg2);
            }
            Gw[(q*4 + 0) * WSTR + nt*16 + r16] = (unsigned short)f2bs(gg0);
            Gw[(q*4 + 1) * WSTR + nt*16 + r16] = (unsigned short)f2bs(gg1);
            Gw[(q*4 + 2) * WSTR + nt*16 + r16] = (unsigned short)f2bs(gg2);
        }
        // same-wave DS ordering: compiler emits lgkmcnt before dependent reads

        // ---- GEMM2: A = G via wave-private LDS transpose, B = W2 ----
        __builtin_amdgcn_s_setprio(1);
        bf16x8 gfr0 = *(const bf16x8*)&Gw[r16 * WSTR + q*8];
        bf16x8 gfr1 = *(const bf16x8*)&Gw[r16 * WSTR + 32 + q*8];
        f32x4 accs[4];
        #pragma unroll
        for (int nt = 0; nt < 4; ++nt) {
            f32x4 acc = {0.f, 0.f, 0.f, 0.f};
            acc = __builtin_amdgcn_mfma_f32_16x16x32_bf16(gfr0, w2f[nt][0], acc, 0, 0, 0);
            acc = __builtin_amdgcn_mfma_f32_16x16x32_bf16(gfr1, w2f[nt][1], acc, 0, 0, 0);
            accs[nt] = acc;
        }
        __builtin_amdgcn_s_setprio(0);
        #pragma unroll
        for (int nt = 0; nt < 4; ++nt) {
            // overwrites Gw bytes already consumed by gfr reads — in-order DS
            #pragma unroll
            for (int r = 0; r < 3; ++r)
                Ow[(q*3 + r) * OSTR + nt*16 + r16] = accs[nt][r] + b2c[nt];
        }

        // ---- coalesced full-line NT stores: 768 consecutive floats per wave-iter ----
        f32x4* gbase = (f32x4*)(out + (long)bb * 192);
        #pragma unroll
        for (int s = 0; s < 3; ++s) {
            int c = lane + 64 * s;
            f32x4 v = *(const f32x4*)&Ow[(c >> 4) * OSTR + (c & 15) * 4];
            __builtin_nontemporal_store(v, gbase + c);
        }
    }
}

extern "C" void kernel_launch(void* const* d_in, const int* in_sizes, int n_in,
                              void* d_out, int out_size, void* d_ws, size_t ws_size,
                              hipStream_t stream)
{
    const float* nodes = (const float*)d_in[0];
    const float* W1    = (const float*)d_in[1];
    const float* b1    = (const float*)d_in[2];
    const float* W2    = (const float*)d_in[3];
    const float* b2    = (const float*)d_in[4];
    const float* ea    = (const float*)d_in[5];
    float* out = (float*)d_out;

    const int groups = (out_size / 64) / 3 / 64;          // 4096 blocks of 64 batches
    edge_mfma21<<<groups, 256, 0, stream>>>(nodes, W1, b1, W2, b2, ea, out);
}

// Round 27
// 80.108 us; speedup vs baseline: 1.1419x; 1.1419x over previous
//
#include <hip/hip_runtime.h>
#include <hip/hip_bf16.h>
#include <math.h>

typedef __attribute__((ext_vector_type(8))) short bf16x8;
typedef __attribute__((ext_vector_type(4))) float f32x4;

#define WSTR 68     // G-buffer row stride in shorts (136B): conflict-free frag reads
#define OSTR 80     // out-stage row stride in floats: 3*80 % 32 == 16 -> 2-way (free)

__device__ __forceinline__ short f2bs(float f) {   // fp32 -> bf16 RNE via hw cvt
    union { __hip_bfloat16 b; short s; } u;
    u.b = __float2bfloat16(f);
    return u.s;
}

__device__ __forceinline__ unsigned short f2b_int(float f) {  // prep path (cold)
    union { float f; unsigned int u; } x; x.f = f;
    unsigned int r = x.u + 0x7FFFu + ((x.u >> 16) & 1u);
    return (unsigned short)(r >> 16);
}

// gelu(x) = x*sigmoid(2y), y = 0.7978845608*x*(1+0.044715*x^2)   (tanh-form, hw exp2)
__device__ __forceinline__ float gelu_t(float x) {
    float x2 = x * x;
    float z  = x * fmaf(0.10294324f, x2, 2.3022082f);
    float e  = __builtin_amdgcn_exp2f(z);
    float r  = __builtin_amdgcn_rcpf(1.0f + e);
    return fmaf(x, -r, x);          // x*(1-r)
}

// prep: w1t[n*64+k] = W1cat[k][n]  (n<64: W1top col n, n>=64: W1bot col n-64)
//       w2t[n*64+k] = W2[k][n];  attn = softmax(edge_attn) rows
__global__ void prep_k(const float* __restrict__ W1, const float* __restrict__ W2,
                       const float* __restrict__ ea, unsigned short* __restrict__ w1t,
                       unsigned short* __restrict__ w2t, float* __restrict__ attn)
{
    int gid = blockIdx.x * 256 + threadIdx.x;
    if (gid < 128 * 64) {
        int n = gid >> 6, k = gid & 63;
        float v = (n < 64) ? W1[k * 64 + n] : W1[(64 + k) * 64 + (n - 64)];
        w1t[gid] = f2b_int(v);
    } else if (gid < 12288) {
        int idx = gid - 8192;
        int n = idx >> 6, k = idx & 63;
        w2t[idx] = f2b_int(W2[k * 64 + n]);
    }
    if (gid < 9) {
        int i = gid / 3, j = gid % 3;
        float e0 = ea[i*3+0], e1 = ea[i*3+1], e2 = ea[i*3+2];
        float mx = fmaxf(e0, fmaxf(e1, e2));
        float d = expf(e0-mx) + expf(e1-mx) + expf(e2-mx);
        attn[gid] = expf(ea[i*3+j] - mx) / d;
    }
}

// W1 fragment from swizzled LDS tile: row in [0,128), 16B-granular XOR swizzle
#define WFRAG(Ws, row, ks) \
    (*(const bf16x8*)&(Ws)[(row) * 64 + ((((ks)*32) + q*8) ^ (((row) & 7) << 3))])

__global__ __launch_bounds__(256, 3)
void edge_mfma20(const float* __restrict__ nodes,
                 const unsigned short* __restrict__ w1t,   // 8192 shorts
                 const unsigned short* __restrict__ w2t,   // 4096 shorts
                 const float* __restrict__ attn9,
                 const float* __restrict__ b1,
                 const float* __restrict__ b2,
                 float* __restrict__ out)
{
    __shared__ __align__(16) unsigned short Ws[8192];   // 16 KB swizzled W1
    __shared__ __align__(16) float Un[4 * 12 * OSTR];   // 15.36 KB: Gw/Ow time-share union
    // total 31744 B -> 5 blocks/CU. Per-wave in-order DS pipe makes the overlay safe.

    const int t = threadIdx.x;
    const int lane = t & 63, wave = t >> 6;
    const int q = lane >> 4, r16 = lane & 15;
    float*          Ow = Un + wave * 12 * OSTR;          // wave-private
    unsigned short* Gw = (unsigned short*)Ow;            // aliased, same bytes

    // ---- stage W1 global -> LDS with 16B-granular XOR swizzle ----
    {
        const ulonglong2* src = (const ulonglong2*)w1t;
        ulonglong2* dst = (ulonglong2*)Ws;
        #pragma unroll
        for (int i = 0; i < 4; ++i) {
            int c = t + i * 256;                          // 1024 chunks
            int n = c >> 3, k8 = c & 7;
            dst[(c & ~7) | (k8 ^ (n & 7))] = src[c];
        }
    }

    // padded tile row r16 -> batch-in-group bA, node-row iA (iA==3 is the dummy row)
    const int bA = r16 >> 2;
    const int iA = r16 & 3;
    const int iAr = (iA == 3) ? 0 : iA;

    // ---- W2 fragments from global (L1-hot; reloads acceptable) ----
    bf16x8 w2f[4][2];
    #pragma unroll
    for (int nt = 0; nt < 4; ++nt)
        #pragma unroll
        for (int ks = 0; ks < 2; ++ks)
            w2f[nt][ks] = *(const bf16x8*)&w2t[(nt*16 + r16) * 64 + ks*32 + q*8];

    // uniform attn weights (SGPR-pinned), per-lane bias slices
    float aw[9];
    #pragma unroll
    for (int i = 0; i < 9; ++i) {
        union { float f; int u; } c; c.f = attn9[i];
        c.u = __builtin_amdgcn_readfirstlane(c.u);
        aw[i] = c.f;
    }
    float b1c[4], b2c[4];
    #pragma unroll
    for (int nt = 0; nt < 4; ++nt) { b1c[nt] = b1[nt*16 + r16]; b2c[nt] = b2[nt*16 + r16]; }

    const int batch0 = blockIdx.x * 64 + wave * 16;

    __syncthreads();   // W1 staged

    #pragma unroll
    for (int mt = 0; mt < 4; ++mt) {
        const int bb = batch0 + mt * 4;                   // this iter's 4 batches

        // ---- X -> A-frags straight from global (k = ks*32 + q*8 + e) ----
        const long rowA = ((long)(bb + bA)) * 3 + iAr;
        const f32x4* xp = (const f32x4*)(nodes + rowA * 64 + q * 8);
        f32x4 x0 = xp[0], x1 = xp[1], x2v = xp[8], x3 = xp[9];
        bf16x8 afr0, afr1;
        #pragma unroll
        for (int e = 0; e < 4; ++e) {
            afr0[e]   = f2bs(x0[e]);  afr0[4+e] = f2bs(x1[e]);
            afr1[e]   = f2bs(x2v[e]); afr1[4+e] = f2bs(x3[e]);
        }

        // ---- GEMM1 + lane-local gelu mix; MFMA cluster under setprio(1) ----
        #pragma unroll
        for (int nt = 0; nt < 4; ++nt) {
            __builtin_amdgcn_s_setprio(1);
            f32x4 z = {0.f, 0.f, 0.f, 0.f};
            z = __builtin_amdgcn_mfma_f32_16x16x32_bf16(afr0, WFRAG(Ws, nt*16 + r16, 0), z, 0, 0, 0);
            z = __builtin_amdgcn_mfma_f32_16x16x32_bf16(afr1, WFRAG(Ws, nt*16 + r16, 1), z, 0, 0, 0);
            f32x4 y = {0.f, 0.f, 0.f, 0.f};
            y = __builtin_amdgcn_mfma_f32_16x16x32_bf16(afr0, WFRAG(Ws, 64 + nt*16 + r16, 0), y, 0, 0, 0);
            y = __builtin_amdgcn_mfma_f32_16x16x32_bf16(afr1, WFRAG(Ws, 64 + nt*16 + r16, 1), y, 0, 0, 0);
            __builtin_amdgcn_s_setprio(0);

            // lane holds batch q: u rows z[0..2], v rows y[0..2], col nt*16+r16
            float u0 = z[0] + b1c[nt], u1 = z[1] + b1c[nt], u2 = z[2] + b1c[nt];
            float gg0 = 0.f, gg1 = 0.f, gg2 = 0.f;
            #pragma unroll
            for (int j = 0; j < 3; ++j) {
                float vj = y[j];
                float gl0 = gelu_t(u0 + vj);
                float gl1 = gelu_t(u1 + vj);
                float gl2 = gelu_t(u2 + vj);
                gg0 = fmaf(aw[0*3+j], gl0, gg0);
                gg1 = fmaf(aw[1*3+j], gl1, gg1);
                gg2 = fmaf(aw[2*3+j], gl2, gg2);
            }
            Gw[(q*4 + 0) * WSTR + nt*16 + r16] = (unsigned short)f2bs(gg0);
            Gw[(q*4 + 1) * WSTR + nt*16 + r16] = (unsigned short)f2bs(gg1);
            Gw[(q*4 + 2) * WSTR + nt*16 + r16] = (unsigned short)f2bs(gg2);
        }
        // same-wave DS ordering: compiler emits lgkmcnt before dependent reads

        // ---- GEMM2: A = G via wave-private LDS transpose, B = W2 in regs ----
        __builtin_amdgcn_s_setprio(1);
        bf16x8 gfr0 = *(const bf16x8*)&Gw[r16 * WSTR + q*8];
        bf16x8 gfr1 = *(const bf16x8*)&Gw[r16 * WSTR + 32 + q*8];
        f32x4 accs[4];
        #pragma unroll
        for (int nt = 0; nt < 4; ++nt) {
            f32x4 acc = {0.f, 0.f, 0.f, 0.f};
            acc = __builtin_amdgcn_mfma_f32_16x16x32_bf16(gfr0, w2f[nt][0], acc, 0, 0, 0);
            acc = __builtin_amdgcn_mfma_f32_16x16x32_bf16(gfr1, w2f[nt][1], acc, 0, 0, 0);
            accs[nt] = acc;
        }
        __builtin_amdgcn_s_setprio(0);
        #pragma unroll
        for (int nt = 0; nt < 4; ++nt) {
            // overwrites Gw bytes already consumed by gfr reads — in-order DS
            #pragma unroll
            for (int r = 0; r < 3; ++r)
                Ow[(q*3 + r) * OSTR + nt*16 + r16] = accs[nt][r] + b2c[nt];
        }

        // ---- coalesced full-line NT stores: 768 consecutive floats per wave-iter ----
        f32x4* gbase = (f32x4*)(out + (long)bb * 192);
        #pragma unroll
        for (int s = 0; s < 3; ++s) {
            int c = lane + 64 * s;
            f32x4 v = *(const f32x4*)&Ow[(c >> 4) * OSTR + (c & 15) * 4];
            __builtin_nontemporal_store(v, gbase + c);
        }
    }
}

extern "C" void kernel_launch(void* const* d_in, const int* in_sizes, int n_in,
                              void* d_out, int out_size, void* d_ws, size_t ws_size,
                              hipStream_t stream)
{
    const float* nodes = (const float*)d_in[0];
    const float* W1    = (const float*)d_in[1];
    const float* b1    = (const float*)d_in[2];
    const float* W2    = (const float*)d_in[3];
    const float* b2    = (const float*)d_in[4];
    const float* ea    = (const float*)d_in[5];
    float* out = (float*)d_out;

    unsigned short* w1t = (unsigned short*)d_ws;          // 8192 shorts (w1cat)
    unsigned short* w2t = w1t + 8192;                     // 4096 shorts (w2)
    float* attn = (float*)(w2t + 4096);                   // 9 floats

    prep_k<<<48, 256, 0, stream>>>(W1, W2, ea, w1t, w2t, attn);

    const int groups = (out_size / 64) / 3 / 64;          // 4096 blocks of 64 batches
    edge_mfma20<<<groups, 256, 0, stream>>>(nodes, w1t, w2t, attn, b1, b2, out);
}